// Round 6
// baseline (276.843 us; speedup 1.0000x reference)
//
#include <hip/hip_runtime.h>
#include <stdint.h>

#define BSZ 64
#define SEQ 197
#define EMB 768
#define NH  12
#define HD  64
#define M_TOK (BSZ*SEQ)      // 12608 token rows
#define SHD (SEQ*HD)         // 12608 elements per (b,h) head matrix

using bf16x8 = __attribute__((ext_vector_type(8))) short;
using f32x4  = __attribute__((ext_vector_type(4))) float;

__device__ __forceinline__ float bflo(uint32_t u) { return __uint_as_float(u << 16); }
__device__ __forceinline__ uint16_t f2bf(float f) {
    uint32_t u = __float_as_uint(f);
    u += 0x7fffu + ((u >> 16) & 1u);   // RNE
    return (uint16_t)(u >> 16);
}

// ---------------------------------------------------------------- convert
struct CvtJob { const float* src; uint16_t* dst; int n8; };
struct CvtJobs { CvtJob j[9]; };

__global__ __launch_bounds__(256) void convert_kernel(CvtJobs jobs)
{
    int idx = blockIdx.x * 256 + threadIdx.x;
    #pragma unroll
    for (int r = 0; r < 9; ++r) {
        const int n8 = jobs.j[r].n8;
        if (idx < n8) {
            const uint4* s4 = (const uint4*)(jobs.j[r].src + (size_t)idx * 8);
            uint4 a = s4[0], b = s4[1];
            uint4 w;
            w.x = (uint32_t)f2bf(__uint_as_float(a.x)) | ((uint32_t)f2bf(__uint_as_float(a.y)) << 16);
            w.y = (uint32_t)f2bf(__uint_as_float(a.z)) | ((uint32_t)f2bf(__uint_as_float(a.w)) << 16);
            w.z = (uint32_t)f2bf(__uint_as_float(b.x)) | ((uint32_t)f2bf(__uint_as_float(b.y)) << 16);
            w.w = (uint32_t)f2bf(__uint_as_float(b.z)) | ((uint32_t)f2bf(__uint_as_float(b.w)) << 16);
            *(uint4*)(jobs.j[r].dst + (size_t)idx * 8) = w;
            return;
        }
        idx -= n8;
    }
}

// ---------------------------------------------------------------- GEMM
struct GemmPtrs {
    const uint16_t* W[3];
    const uint16_t* b[3];
    void*           out[3];
};

// C[m][n] = sum_k A[m][k]*W[n][k] + bias[n]  (NT, bf16 in, fp32 acc)
// Round-6: (a) XOR bank swizzle on staging source addresses (row stride 64 B
// put 16 lanes on 2 bank groups -> 8-way conflict; swizzle spreads to 8 groups
// -> 2-way = free). (b) Double-buffered LDS with raw s_barrier + vmcnt(4):
// next tile's global_load_lds stay in flight across the barrier (m139/AITER
// pattern; __syncthreads would force vmcnt(0) drain).
__global__ __launch_bounds__(256) void gemm_bias_nt(const uint16_t* __restrict__ A,
                                                    GemmPtrs p, int M, int outf32)
{
    __shared__ __align__(16) uint16_t sA[2][128 * 32];
    __shared__ __align__(16) uint16_t sB[2][128 * 32];

    const int z = blockIdx.z;
    const uint16_t* __restrict__ W    = p.W[z];
    const uint16_t* __restrict__ bias = p.b[z];

    const int m0   = blockIdx.x * 128;
    const int n0   = blockIdx.y * 128;
    const int tid  = threadIdx.x;
    const int lane = tid & 63;
    const int wave = tid >> 6;
    const int wr = wave >> 1, wc = wave & 1;
    const int l15 = lane & 15;
    const int kq  = lane >> 4;

    // staging: chunk c (0..511) -> LDS slot c*16B; source chunk XOR-swizzled
    const int c0 = tid, c1 = tid + 256;
    const int row0 = c0 >> 2, kc0 = c0 & 3;
    const int row1 = c1 >> 2, kc1 = c1 & 3;
    const int ks0 = (kc0 ^ ((row0 >> 1) & 3)) * 8;   // swizzled k-offset (elems)
    const int ks1 = (kc1 ^ ((row1 >> 1) & 3)) * 8;
    int ga0 = m0 + row0; if (ga0 >= M) ga0 = M - 1;
    int ga1 = m0 + row1; if (ga1 >= M) ga1 = M - 1;
    const uint16_t* a0p = A + (size_t)ga0 * EMB + ks0;
    const uint16_t* a1p = A + (size_t)ga1 * EMB + ks1;
    const uint16_t* b0p = W + (size_t)(n0 + row0) * EMB + ks0;
    const uint16_t* b1p = W + (size_t)(n0 + row1) * EMB + ks1;

    // reader swizzle: row r=16i+l15 -> (r>>1)&3 == (l15>>1)&3 (i-independent)
    const int kqs = (kq ^ ((l15 >> 1) & 3)) * 8;

    f32x4 acc[4][4] = {};

    #define STAGE(buf, k0)                                                        \
        do {                                                                      \
            __builtin_amdgcn_global_load_lds(                                     \
                (const __attribute__((address_space(1))) void*)(a0p + (k0)),      \
                (__attribute__((address_space(3))) void*)(sA[buf] + c0 * 8), 16, 0, 0); \
            __builtin_amdgcn_global_load_lds(                                     \
                (const __attribute__((address_space(1))) void*)(a1p + (k0)),      \
                (__attribute__((address_space(3))) void*)(sA[buf] + c1 * 8), 16, 0, 0); \
            __builtin_amdgcn_global_load_lds(                                     \
                (const __attribute__((address_space(1))) void*)(b0p + (k0)),      \
                (__attribute__((address_space(3))) void*)(sB[buf] + c0 * 8), 16, 0, 0); \
            __builtin_amdgcn_global_load_lds(                                     \
                (const __attribute__((address_space(1))) void*)(b1p + (k0)),      \
                (__attribute__((address_space(3))) void*)(sB[buf] + c1 * 8), 16, 0, 0); \
        } while (0)

    STAGE(0, 0);

    const int NIT = EMB / 32;   // 24
    for (int it = 0; it < NIT; ++it) {
        const int cur = it & 1;
        if (it + 1 < NIT) {
            STAGE(cur ^ 1, (it + 1) * 32);
            asm volatile("s_waitcnt vmcnt(4)" ::: "memory");  // tile `it` landed; next in flight
        } else {
            asm volatile("s_waitcnt vmcnt(0)" ::: "memory");
        }
        __builtin_amdgcn_s_barrier();
        asm volatile("" ::: "memory");

        bf16x8 af[4], bfr[4];
        #pragma unroll
        for (int i = 0; i < 4; ++i)
            af[i] = *(const bf16x8*)(sA[cur] + (64 * wr + 16 * i + l15) * 32 + kqs);
        #pragma unroll
        for (int j = 0; j < 4; ++j)
            bfr[j] = *(const bf16x8*)(sB[cur] + (64 * wc + 16 * j + l15) * 32 + kqs);

        #pragma unroll
        for (int i = 0; i < 4; ++i)
            #pragma unroll
            for (int j = 0; j < 4; ++j)
                acc[i][j] = __builtin_amdgcn_mfma_f32_16x16x32_bf16(af[i], bfr[j], acc[i][j], 0, 0, 0);

        asm volatile("s_waitcnt lgkmcnt(0)" ::: "memory");    // ds_reads done before
        __builtin_amdgcn_s_barrier();                         // buffer reuse
        asm volatile("" ::: "memory");
    }
    #undef STAGE

    // C/D: col = lane&15, row = (lane>>4)*4 + reg
    #pragma unroll
    for (int j = 0; j < 4; ++j) {
        int n = n0 + 64 * wc + 16 * j + l15;
        float bv = bflo((uint32_t)bias[n]);
        #pragma unroll
        for (int i = 0; i < 4; ++i) {
            #pragma unroll
            for (int r = 0; r < 4; ++r) {
                int m = m0 + 64 * wr + 16 * i + kq * 4 + r;
                if (m < M) {
                    float v = acc[i][j][r] + bv;
                    if (outf32) ((float*)p.out[z])[(size_t)m * EMB + n] = v;
                    else        ((uint16_t*)p.out[z])[(size_t)m * EMB + n] = f2bf(v);
                }
            }
        }
    }
}

// ---------------------------------------------------------------- attention (MFMA)
#define RV 264   // sVt row stride (keys)
#define RP 72    // sP row stride
__global__ __launch_bounds__(256) void attn_kernel(const uint16_t* __restrict__ Qg,
                                                   const uint16_t* __restrict__ Kg,
                                                   const uint16_t* __restrict__ Vg,
                                                   uint16_t* __restrict__ Og)
{
    __shared__ __align__(16) uint16_t sVt[HD * RV];
    __shared__ __align__(16) uint16_t sP[4][64 * RP];

    const int bh  = blockIdx.x;
    const size_t base = (size_t)bh * SHD;
    const int tid  = threadIdx.x;
    const int lane = tid & 63;
    const int w    = tid >> 6;
    const int l15  = lane & 15;
    const int kq   = lane >> 4;
    uint16_t* sPw = sP[w];

    {
        int r = tid >> 2, t4 = tid & 3;
        for (int c = SEQ + t4; c < RV; c += 4) sVt[r * RV + c] = 0;
    }
    for (int idx = tid; idx < SHD / 8; idx += 256) {
        int key = idx >> 3, dc = idx & 7;
        uint4 v = ((const uint4*)(Vg + base))[idx];
        uint16_t e[8];
        *(uint4*)e = v;
        #pragma unroll
        for (int j = 0; j < 8; ++j) sVt[(dc * 8 + j) * RV + key] = e[j];
    }

    bf16x8 aq[4][2];
    #pragma unroll
    for (int mi = 0; mi < 4; ++mi) {
        int m = 64 * w + 16 * mi + l15; if (m >= SEQ) m = SEQ - 1;
        const uint16_t* qp = Qg + base + (size_t)m * HD + kq * 8;
        aq[mi][0] = *(const bf16x8*)(qp);
        aq[mi][1] = *(const bf16x8*)(qp + 32);
    }

    bf16x8 ones;
    #pragma unroll
    for (int j = 0; j < 8; ++j) ones[j] = (short)0x3F80;

    f32x4 oacc[4][4] = {};
    f32x4 lacc[4]    = {};

    __syncthreads();   // sVt ready

    for (int c = 0; c < 4; ++c) {
        bf16x8 bk[4][2];
        #pragma unroll
        for (int ni = 0; ni < 4; ++ni) {
            int key = 64 * c + 16 * ni + l15; if (key >= SEQ) key = SEQ - 1;
            const uint16_t* kp = Kg + base + (size_t)key * HD + kq * 8;
            bk[ni][0] = *(const bf16x8*)(kp);
            bk[ni][1] = *(const bf16x8*)(kp + 32);
        }
        #pragma unroll
        for (int mi = 0; mi < 4; ++mi) {
            #pragma unroll
            for (int ni = 0; ni < 4; ++ni) {
                f32x4 s = {};
                s = __builtin_amdgcn_mfma_f32_16x16x32_bf16(aq[mi][0], bk[ni][0], s, 0, 0, 0);
                s = __builtin_amdgcn_mfma_f32_16x16x32_bf16(aq[mi][1], bk[ni][1], s, 0, 0, 0);
                int col = 16 * ni + l15;
                int key = 64 * c + col;
                #pragma unroll
                for (int r = 0; r < 4; ++r) {
                    float pv = (key < SEQ) ? __expf(fminf(s[r], 80.f)) : 0.f;
                    sPw[(16 * mi + kq * 4 + r) * RP + col] = f2bf(pv);
                }
            }
        }

        bf16x8 bv[2][4];
        #pragma unroll
        for (int kk = 0; kk < 2; ++kk)
            #pragma unroll
            for (int ni = 0; ni < 4; ++ni)
                bv[kk][ni] = *(const bf16x8*)(sVt + (16 * ni + l15) * RV + c * 64 + kk * 32 + kq * 8);

        #pragma unroll
        for (int mi = 0; mi < 4; ++mi) {
            #pragma unroll
            for (int kk = 0; kk < 2; ++kk) {
                bf16x8 ap = *(const bf16x8*)(sPw + (16 * mi + l15) * RP + kk * 32 + kq * 8);
                lacc[mi] = __builtin_amdgcn_mfma_f32_16x16x32_bf16(ap, ones, lacc[mi], 0, 0, 0);
                #pragma unroll
                for (int ni = 0; ni < 4; ++ni)
                    oacc[mi][ni] = __builtin_amdgcn_mfma_f32_16x16x32_bf16(ap, bv[kk][ni], oacc[mi][ni], 0, 0, 0);
            }
        }
    }

    #pragma unroll
    for (int mi = 0; mi < 4; ++mi) {
        #pragma unroll
        for (int r = 0; r < 4; ++r) {
            int m = 64 * w + 16 * mi + kq * 4 + r;
            if (m < SEQ) {
                float scale = 1.f / (lacc[mi][r] * 27.712812921102035f);
                #pragma unroll
                for (int ni = 0; ni < 4; ++ni)
                    Og[base + (size_t)m * HD + 16 * ni + l15] = f2bf(oacc[mi][ni][r] * scale);
            }
        }
    }
}

// ---------------------------------------------------------------- launch
extern "C" void kernel_launch(void* const* d_in, const int* in_sizes, int n_in,
                              void* d_out, int out_size, void* d_ws, size_t ws_size,
                              hipStream_t stream)
{
    const size_t NX = (size_t)M_TOK * EMB;
    const size_t NW = (size_t)EMB * EMB;
    const size_t NB = EMB;

    uint16_t* xbf = (uint16_t*)d_ws;
    uint16_t* Wbf[4]; uint16_t* bbf[4];
    uint16_t* cur = xbf + NX;
    for (int i = 0; i < 4; ++i) { Wbf[i] = cur; cur += NW; }
    for (int i = 0; i < 4; ++i) { bbf[i] = cur; cur += NB; }
    uint16_t* Qw = cur;
    uint16_t* Kw = Qw + NX;
    uint16_t* Vw = Kw + NX;

    const size_t need_primary  = 2 * (NX + 4 * NW + 4 * NB + 3 * NX);
    const size_t need_fallback = need_primary - 2 * NX;
    if (ws_size < need_fallback) return;
    if (ws_size < need_primary) Vw = (uint16_t*)d_out;

    CvtJobs jobs;
    jobs.j[0] = { (const float*)d_in[0], xbf,    (int)(NX / 8) };
    jobs.j[1] = { (const float*)d_in[1], Wbf[0], (int)(NW / 8) };
    jobs.j[2] = { (const float*)d_in[3], Wbf[1], (int)(NW / 8) };
    jobs.j[3] = { (const float*)d_in[5], Wbf[2], (int)(NW / 8) };
    jobs.j[4] = { (const float*)d_in[7], Wbf[3], (int)(NW / 8) };
    jobs.j[5] = { (const float*)d_in[2], bbf[0], (int)(NB / 8) };
    jobs.j[6] = { (const float*)d_in[4], bbf[1], (int)(NB / 8) };
    jobs.j[7] = { (const float*)d_in[6], bbf[2], (int)(NB / 8) };
    jobs.j[8] = { (const float*)d_in[8], bbf[3], (int)(NB / 8) };
    const int total8 = (int)((NX + 4 * NW + 4 * NB) / 8);
    convert_kernel<<<(total8 + 255) / 256, 256, 0, stream>>>(jobs);

    GemmPtrs qkv;
    qkv.W[0] = Wbf[0]; qkv.W[1] = Wbf[1]; qkv.W[2] = Wbf[2];
    qkv.b[0] = bbf[0]; qkv.b[1] = bbf[1]; qkv.b[2] = bbf[2];
    qkv.out[0] = Qw; qkv.out[1] = Kw; qkv.out[2] = Vw;
    dim3 g1((M_TOK + 127) / 128, EMB / 128, 3);
    gemm_bias_nt<<<g1, 256, 0, stream>>>(xbf, qkv, M_TOK, 0);

    attn_kernel<<<dim3(BSZ * NH), 256, 0, stream>>>(Qw, Kw, Vw, Qw);

    GemmPtrs pr;
    pr.W[0] = pr.W[1] = pr.W[2] = Wbf[3];
    pr.b[0] = pr.b[1] = pr.b[2] = bbf[3];
    pr.out[0] = pr.out[1] = pr.out[2] = d_out;
    dim3 g2((M_TOK + 127) / 128, EMB / 128, 1);
    gemm_bias_nt<<<g2, 256, 0, stream>>>(Qw, pr, M_TOK, 1);
}

// Round 7
// 264.752 us; speedup vs baseline: 1.0457x; 1.0457x over previous
//
#include <hip/hip_runtime.h>
#include <stdint.h>

#define BSZ 64
#define SEQ 197
#define EMB 768
#define NH  12
#define HD  64
#define M_TOK (BSZ*SEQ)      // 12608 token rows
#define SHD (SEQ*HD)         // 12608 elements per (b,h) head matrix

using bf16x8 = __attribute__((ext_vector_type(8))) short;
using f32x4  = __attribute__((ext_vector_type(4))) float;

__device__ __forceinline__ float bflo(uint32_t u) { return __uint_as_float(u << 16); }
__device__ __forceinline__ uint16_t f2bf(float f) {
    uint32_t u = __float_as_uint(f);
    u += 0x7fffu + ((u >> 16) & 1u);   // RNE
    return (uint16_t)(u >> 16);
}

// ---------------------------------------------------------------- convert
struct CvtJob { const float* src; uint16_t* dst; int n8; };
struct CvtJobs { CvtJob j[9]; };

__global__ __launch_bounds__(256) void convert_kernel(CvtJobs jobs)
{
    int idx = blockIdx.x * 256 + threadIdx.x;
    #pragma unroll
    for (int r = 0; r < 9; ++r) {
        const int n8 = jobs.j[r].n8;
        if (idx < n8) {
            const uint4* s4 = (const uint4*)(jobs.j[r].src + (size_t)idx * 8);
            uint4 a = s4[0], b = s4[1];
            uint4 w;
            w.x = (uint32_t)f2bf(__uint_as_float(a.x)) | ((uint32_t)f2bf(__uint_as_float(a.y)) << 16);
            w.y = (uint32_t)f2bf(__uint_as_float(a.z)) | ((uint32_t)f2bf(__uint_as_float(a.w)) << 16);
            w.z = (uint32_t)f2bf(__uint_as_float(b.x)) | ((uint32_t)f2bf(__uint_as_float(b.y)) << 16);
            w.w = (uint32_t)f2bf(__uint_as_float(b.z)) | ((uint32_t)f2bf(__uint_as_float(b.w)) << 16);
            *(uint4*)(jobs.j[r].dst + (size_t)idx * 8) = w;
            return;
        }
        idx -= n8;
    }
}

// ---------------------------------------------------------------- GEMM
struct GemmPtrs {
    const uint16_t* W[3];
    const uint16_t* b[3];
    void*           out[3];
};

// C[m][n] = sum_k A[m][k]*W[n][k] + bias[n]  (NT, bf16 in, fp32 acc)
// Round-7: 1D grid + XCD-aware swizzle. HW assigns block -> XCD as (flat % 8);
// we invert that so all 18 (n,z) tiles of one m-tile run on ONE XCD: A rows
// fetched from HBM once per XCD (then L2-hit, ~200cy vs ~900cy), weights stay
// L2-resident. Round-6 counters: FETCH 187 MB vs ~23 ideal, no pipe >45% ->
// latency-bound on HBM misses; this attacks the miss rate, not the pipeline.
__global__ __launch_bounds__(256) void gemm_bias_nt(const uint16_t* __restrict__ A,
                                                    GemmPtrs p, int M,
                                                    int total, int nz, int outf32)
{
    __shared__ __align__(16) uint16_t sA[2][128 * 32];
    __shared__ __align__(16) uint16_t sB[2][128 * 32];

    // ---- XCD swizzle: flat -> wid such that same-XCD wids are contiguous ----
    const int flat  = blockIdx.x;
    const int xcd   = flat & 7;
    const int local = flat >> 3;
    const int cb = total >> 3, r8 = total & 7;
    const int start = xcd * cb + (xcd < r8 ? xcd : r8);
    const int wid = start + local;
    const int per_m = 6 * nz;                 // (n,z) combos per m-tile
    const int m_idx = wid / per_m;
    const int rem   = wid - m_idx * per_m;
    const int z     = rem / 6;
    const int n_idx = rem - z * 6;

    const uint16_t* __restrict__ W    = p.W[z];
    const uint16_t* __restrict__ bias = p.b[z];

    const int m0   = m_idx * 128;
    const int n0   = n_idx * 128;
    const int tid  = threadIdx.x;
    const int lane = tid & 63;
    const int wave = tid >> 6;
    const int wr = wave >> 1, wc = wave & 1;
    const int l15 = lane & 15;
    const int kq  = lane >> 6 ? 0 : lane >> 4;   // kq = lane>>4 (0..3)

    const int c0 = tid, c1 = tid + 256;
    const int row0 = c0 >> 2, kc0 = c0 & 3;
    const int row1 = c1 >> 2, kc1 = c1 & 3;
    const int ks0 = (kc0 ^ ((row0 >> 1) & 3)) * 8;   // bank-swizzled k-offset
    const int ks1 = (kc1 ^ ((row1 >> 1) & 3)) * 8;
    int ga0 = m0 + row0; if (ga0 >= M) ga0 = M - 1;
    int ga1 = m0 + row1; if (ga1 >= M) ga1 = M - 1;
    const uint16_t* a0p = A + (size_t)ga0 * EMB + ks0;
    const uint16_t* a1p = A + (size_t)ga1 * EMB + ks1;
    const uint16_t* b0p = W + (size_t)(n0 + row0) * EMB + ks0;
    const uint16_t* b1p = W + (size_t)(n0 + row1) * EMB + ks1;

    const int kqs = ((lane >> 4) ^ ((l15 >> 1) & 3)) * 8;   // reader swizzle

    f32x4 acc[4][4] = {};

    #define STAGE(buf, k0)                                                        \
        do {                                                                      \
            __builtin_amdgcn_global_load_lds(                                     \
                (const __attribute__((address_space(1))) void*)(a0p + (k0)),      \
                (__attribute__((address_space(3))) void*)(sA[buf] + c0 * 8), 16, 0, 0); \
            __builtin_amdgcn_global_load_lds(                                     \
                (const __attribute__((address_space(1))) void*)(a1p + (k0)),      \
                (__attribute__((address_space(3))) void*)(sA[buf] + c1 * 8), 16, 0, 0); \
            __builtin_amdgcn_global_load_lds(                                     \
                (const __attribute__((address_space(1))) void*)(b0p + (k0)),      \
                (__attribute__((address_space(3))) void*)(sB[buf] + c0 * 8), 16, 0, 0); \
            __builtin_amdgcn_global_load_lds(                                     \
                (const __attribute__((address_space(1))) void*)(b1p + (k0)),      \
                (__attribute__((address_space(3))) void*)(sB[buf] + c1 * 8), 16, 0, 0); \
        } while (0)

    STAGE(0, 0);

    const int NIT = EMB / 32;   // 24
    for (int it = 0; it < NIT; ++it) {
        const int cur = it & 1;
        if (it + 1 < NIT) {
            STAGE(cur ^ 1, (it + 1) * 32);
            asm volatile("s_waitcnt vmcnt(4)" ::: "memory");
        } else {
            asm volatile("s_waitcnt vmcnt(0)" ::: "memory");
        }
        __builtin_amdgcn_s_barrier();
        asm volatile("" ::: "memory");

        bf16x8 af[4], bfr[4];
        #pragma unroll
        for (int i = 0; i < 4; ++i)
            af[i] = *(const bf16x8*)(sA[cur] + (64 * wr + 16 * i + l15) * 32 + kqs);
        #pragma unroll
        for (int j = 0; j < 4; ++j)
            bfr[j] = *(const bf16x8*)(sB[cur] + (64 * wc + 16 * j + l15) * 32 + kqs);

        #pragma unroll
        for (int i = 0; i < 4; ++i)
            #pragma unroll
            for (int j = 0; j < 4; ++j)
                acc[i][j] = __builtin_amdgcn_mfma_f32_16x16x32_bf16(af[i], bfr[j], acc[i][j], 0, 0, 0);

        asm volatile("s_waitcnt lgkmcnt(0)" ::: "memory");
        __builtin_amdgcn_s_barrier();
        asm volatile("" ::: "memory");
    }
    #undef STAGE

    // C/D: col = lane&15, row = (lane>>4)*4 + reg
    const int kq4 = (lane >> 4) * 4;
    #pragma unroll
    for (int j = 0; j < 4; ++j) {
        int n = n0 + 64 * wc + 16 * j + l15;
        float bv = bflo((uint32_t)bias[n]);
        #pragma unroll
        for (int i = 0; i < 4; ++i) {
            #pragma unroll
            for (int r = 0; r < 4; ++r) {
                int m = m0 + 64 * wr + 16 * i + kq4 + r;
                if (m < M) {
                    float v = acc[i][j][r] + bv;
                    if (outf32) ((float*)p.out[z])[(size_t)m * EMB + n] = v;
                    else        ((uint16_t*)p.out[z])[(size_t)m * EMB + n] = f2bf(v);
                }
            }
        }
    }
}

// ---------------------------------------------------------------- attention (MFMA)
#define RV 264   // sVt row stride (keys)
#define RP 72    // sP row stride
__global__ __launch_bounds__(256) void attn_kernel(const uint16_t* __restrict__ Qg,
                                                   const uint16_t* __restrict__ Kg,
                                                   const uint16_t* __restrict__ Vg,
                                                   uint16_t* __restrict__ Og)
{
    __shared__ __align__(16) uint16_t sVt[HD * RV];
    __shared__ __align__(16) uint16_t sP[4][64 * RP];

    const int bh  = blockIdx.x;
    const size_t base = (size_t)bh * SHD;
    const int tid  = threadIdx.x;
    const int lane = tid & 63;
    const int w    = tid >> 6;
    const int l15  = lane & 15;
    const int kq   = lane >> 4;
    uint16_t* sPw = sP[w];

    {
        int r = tid >> 2, t4 = tid & 3;
        for (int c = SEQ + t4; c < RV; c += 4) sVt[r * RV + c] = 0;
    }
    for (int idx = tid; idx < SHD / 8; idx += 256) {
        int key = idx >> 3, dc = idx & 7;
        uint4 v = ((const uint4*)(Vg + base))[idx];
        uint16_t e[8];
        *(uint4*)e = v;
        #pragma unroll
        for (int j = 0; j < 8; ++j) sVt[(dc * 8 + j) * RV + key] = e[j];
    }

    bf16x8 aq[4][2];
    #pragma unroll
    for (int mi = 0; mi < 4; ++mi) {
        int m = 64 * w + 16 * mi + l15; if (m >= SEQ) m = SEQ - 1;
        const uint16_t* qp = Qg + base + (size_t)m * HD + kq * 8;
        aq[mi][0] = *(const bf16x8*)(qp);
        aq[mi][1] = *(const bf16x8*)(qp + 32);
    }

    bf16x8 ones;
    #pragma unroll
    for (int j = 0; j < 8; ++j) ones[j] = (short)0x3F80;

    f32x4 oacc[4][4] = {};
    f32x4 lacc[4]    = {};

    __syncthreads();   // sVt ready

    for (int c = 0; c < 4; ++c) {
        bf16x8 bk[4][2];
        #pragma unroll
        for (int ni = 0; ni < 4; ++ni) {
            int key = 64 * c + 16 * ni + l15; if (key >= SEQ) key = SEQ - 1;
            const uint16_t* kp = Kg + base + (size_t)key * HD + kq * 8;
            bk[ni][0] = *(const bf16x8*)(kp);
            bk[ni][1] = *(const bf16x8*)(kp + 32);
        }
        #pragma unroll
        for (int mi = 0; mi < 4; ++mi) {
            #pragma unroll
            for (int ni = 0; ni < 4; ++ni) {
                f32x4 s = {};
                s = __builtin_amdgcn_mfma_f32_16x16x32_bf16(aq[mi][0], bk[ni][0], s, 0, 0, 0);
                s = __builtin_amdgcn_mfma_f32_16x16x32_bf16(aq[mi][1], bk[ni][1], s, 0, 0, 0);
                int col = 16 * ni + l15;
                int key = 64 * c + col;
                #pragma unroll
                for (int r = 0; r < 4; ++r) {
                    float pv = (key < SEQ) ? __expf(fminf(s[r], 80.f)) : 0.f;
                    sPw[(16 * mi + kq * 4 + r) * RP + col] = f2bf(pv);
                }
            }
        }

        bf16x8 bv[2][4];
        #pragma unroll
        for (int kk = 0; kk < 2; ++kk)
            #pragma unroll
            for (int ni = 0; ni < 4; ++ni)
                bv[kk][ni] = *(const bf16x8*)(sVt + (16 * ni + l15) * RV + c * 64 + kk * 32 + kq * 8);

        #pragma unroll
        for (int mi = 0; mi < 4; ++mi) {
            #pragma unroll
            for (int kk = 0; kk < 2; ++kk) {
                bf16x8 ap = *(const bf16x8*)(sPw + (16 * mi + l15) * RP + kk * 32 + kq * 8);
                lacc[mi] = __builtin_amdgcn_mfma_f32_16x16x32_bf16(ap, ones, lacc[mi], 0, 0, 0);
                #pragma unroll
                for (int ni = 0; ni < 4; ++ni)
                    oacc[mi][ni] = __builtin_amdgcn_mfma_f32_16x16x32_bf16(ap, bv[kk][ni], oacc[mi][ni], 0, 0, 0);
            }
        }
    }

    #pragma unroll
    for (int mi = 0; mi < 4; ++mi) {
        #pragma unroll
        for (int r = 0; r < 4; ++r) {
            int m = 64 * w + 16 * mi + kq * 4 + r;
            if (m < SEQ) {
                float scale = 1.f / (lacc[mi][r] * 27.712812921102035f);
                #pragma unroll
                for (int ni = 0; ni < 4; ++ni)
                    Og[base + (size_t)m * HD + 16 * ni + l15] = f2bf(oacc[mi][ni][r] * scale);
            }
        }
    }
}

// ---------------------------------------------------------------- launch
extern "C" void kernel_launch(void* const* d_in, const int* in_sizes, int n_in,
                              void* d_out, int out_size, void* d_ws, size_t ws_size,
                              hipStream_t stream)
{
    const size_t NX = (size_t)M_TOK * EMB;
    const size_t NW = (size_t)EMB * EMB;
    const size_t NB = EMB;

    uint16_t* xbf = (uint16_t*)d_ws;
    uint16_t* Wbf[4]; uint16_t* bbf[4];
    uint16_t* cur = xbf + NX;
    for (int i = 0; i < 4; ++i) { Wbf[i] = cur; cur += NW; }
    for (int i = 0; i < 4; ++i) { bbf[i] = cur; cur += NB; }
    uint16_t* Qw = cur;
    uint16_t* Kw = Qw + NX;
    uint16_t* Vw = Kw + NX;

    const size_t need_primary  = 2 * (NX + 4 * NW + 4 * NB + 3 * NX);
    const size_t need_fallback = need_primary - 2 * NX;
    if (ws_size < need_fallback) return;
    if (ws_size < need_primary) Vw = (uint16_t*)d_out;

    CvtJobs jobs;
    jobs.j[0] = { (const float*)d_in[0], xbf,    (int)(NX / 8) };
    jobs.j[1] = { (const float*)d_in[1], Wbf[0], (int)(NW / 8) };
    jobs.j[2] = { (const float*)d_in[3], Wbf[1], (int)(NW / 8) };
    jobs.j[3] = { (const float*)d_in[5], Wbf[2], (int)(NW / 8) };
    jobs.j[4] = { (const float*)d_in[7], Wbf[3], (int)(NW / 8) };
    jobs.j[5] = { (const float*)d_in[2], bbf[0], (int)(NB / 8) };
    jobs.j[6] = { (const float*)d_in[4], bbf[1], (int)(NB / 8) };
    jobs.j[7] = { (const float*)d_in[6], bbf[2], (int)(NB / 8) };
    jobs.j[8] = { (const float*)d_in[8], bbf[3], (int)(NB / 8) };
    const int total8 = (int)((NX + 4 * NW + 4 * NB) / 8);
    convert_kernel<<<(total8 + 255) / 256, 256, 0, stream>>>(jobs);

    const int MT = (M_TOK + 127) / 128;   // 99 m-tiles

    GemmPtrs qkv;
    qkv.W[0] = Wbf[0]; qkv.W[1] = Wbf[1]; qkv.W[2] = Wbf[2];
    qkv.b[0] = bbf[0]; qkv.b[1] = bbf[1]; qkv.b[2] = bbf[2];
    qkv.out[0] = Qw; qkv.out[1] = Kw; qkv.out[2] = Vw;
    const int tot1 = MT * 6 * 3;
    gemm_bias_nt<<<tot1, 256, 0, stream>>>(xbf, qkv, M_TOK, tot1, 3, 0);

    attn_kernel<<<dim3(BSZ * NH), 256, 0, stream>>>(Qw, Kw, Vw, Qw);

    GemmPtrs pr;
    pr.W[0] = pr.W[1] = pr.W[2] = Wbf[3];
    pr.b[0] = pr.b[1] = pr.b[2] = bbf[3];
    pr.out[0] = pr.out[1] = pr.out[2] = d_out;
    const int tot2 = MT * 6 * 1;
    gemm_bias_nt<<<tot2, 256, 0, stream>>>(Qw, pr, M_TOK, tot2, 1, 1);
}

// Round 8
// 258.762 us; speedup vs baseline: 1.0699x; 1.0231x over previous
//
#include <hip/hip_runtime.h>
#include <stdint.h>

#define BSZ 64
#define SEQ 197
#define EMB 768
#define NH  12
#define HD  64
#define M_TOK (BSZ*SEQ)      // 12608 token rows
#define SHD (SEQ*HD)         // 12608 elements per (b,h) head matrix

using bf16x8 = __attribute__((ext_vector_type(8))) short;
using f32x4  = __attribute__((ext_vector_type(4))) float;

__device__ __forceinline__ float bflo(uint32_t u) { return __uint_as_float(u << 16); }
__device__ __forceinline__ uint16_t f2bf(float f) {
    uint32_t u = __float_as_uint(f);
    u += 0x7fffu + ((u >> 16) & 1u);   // RNE
    return (uint16_t)(u >> 16);
}

// ---------------------------------------------------------------- convert
struct CvtJob { const float* src; uint16_t* dst; int n8; };
struct CvtJobs { CvtJob j[9]; };

__global__ __launch_bounds__(256) void convert_kernel(CvtJobs jobs)
{
    int idx = blockIdx.x * 256 + threadIdx.x;
    #pragma unroll
    for (int r = 0; r < 9; ++r) {
        const int n8 = jobs.j[r].n8;
        if (idx < n8) {
            const uint4* s4 = (const uint4*)(jobs.j[r].src + (size_t)idx * 8);
            uint4 a = s4[0], b = s4[1];
            uint4 w;
            w.x = (uint32_t)f2bf(__uint_as_float(a.x)) | ((uint32_t)f2bf(__uint_as_float(a.y)) << 16);
            w.y = (uint32_t)f2bf(__uint_as_float(a.z)) | ((uint32_t)f2bf(__uint_as_float(a.w)) << 16);
            w.z = (uint32_t)f2bf(__uint_as_float(b.x)) | ((uint32_t)f2bf(__uint_as_float(b.y)) << 16);
            w.w = (uint32_t)f2bf(__uint_as_float(b.z)) | ((uint32_t)f2bf(__uint_as_float(b.w)) << 16);
            *(uint4*)(jobs.j[r].dst + (size_t)idx * 8) = w;
            return;
        }
        idx -= n8;
    }
}

// ---------------------------------------------------------------- GEMM
struct GemmPtrs {
    const uint16_t* W[3];
    const uint16_t* b[3];
    void*           out[3];
};

// C[m][n] = sum_k A[m][k]*W[n][k] + bias[n]  (NT, bf16 in, fp32 acc)
// Round-8: 128m x 256n tile, 32 MFMA/wave/iter (2x round-7). Rationale: the
// per-K-iteration wall (~800-1100 cy; barrier+LDS turnaround+L2 latency at
// 2 blocks/CU) is structure-invariant (r5/r6/r7 all ~100us; matches m97's own
// per-iter wall) — so buy 2x the MFMA per wall-window instead of shaving the
// wall. per_m = n-tiles per m-tile (9 for fused QKV: z = nt/3, n0=(nt%3)*256;
// 3 for proj). XCD swizzle + bank swizzle + dbuf/vmcnt kept (FETCH/conflict
// counters validated them).
__global__ __launch_bounds__(256, 2) void gemm_bias_nt(const uint16_t* __restrict__ A,
                                                       GemmPtrs p, int M,
                                                       int total, int per_m, int outf32)
{
    __shared__ __align__(16) uint16_t sA[2][128 * 32];   // 16 KB
    __shared__ __align__(16) uint16_t sB[2][256 * 32];   // 32 KB

    // ---- XCD swizzle: same-m-tile blocks land on one XCD ----
    const int flat  = blockIdx.x;
    const int xcd   = flat & 7;
    const int local = flat >> 3;
    const int cbk = total >> 3, r8 = total & 7;
    const int start = xcd * cbk + (xcd < r8 ? xcd : r8);
    const int wid = start + local;
    const int m_idx = wid / per_m;
    const int nt    = wid - m_idx * per_m;
    const int z     = nt / 3;            // per_m=3 -> always 0
    const int n0    = (nt - z * 3) * 256;

    const uint16_t* __restrict__ W    = p.W[z];
    const uint16_t* __restrict__ bias = p.b[z];

    const int m0   = m_idx * 128;
    const int tid  = threadIdx.x;
    const int lane = tid & 63;
    const int wave = tid >> 6;
    const int wr = wave >> 1, wc = wave & 1;   // 2x2 waves: 64m x 128n each
    const int l15 = lane & 15;
    const int kq  = lane >> 4;

    // ---- staging: A 512 chunks (2/thread), B 1024 chunks (4/thread) ----
    const int a_c0 = tid, a_c1 = tid + 256;
    const int ar0 = a_c0 >> 2, akc0 = a_c0 & 3;
    const int ar1 = a_c1 >> 2, akc1 = a_c1 & 3;
    const int aks0 = (akc0 ^ ((ar0 >> 1) & 3)) * 8;
    const int aks1 = (akc1 ^ ((ar1 >> 1) & 3)) * 8;
    int ga0 = m0 + ar0; if (ga0 >= M) ga0 = M - 1;
    int ga1 = m0 + ar1; if (ga1 >= M) ga1 = M - 1;
    const uint16_t* a0p = A + (size_t)ga0 * EMB + aks0;
    const uint16_t* a1p = A + (size_t)ga1 * EMB + aks1;

    const uint16_t* bp[4];
    int b_c[4];
    #pragma unroll
    for (int q = 0; q < 4; ++q) {
        int c = tid + 256 * q;
        b_c[q] = c;
        int row = c >> 2, kc = c & 3;
        int ks = (kc ^ ((row >> 1) & 3)) * 8;
        bp[q] = W + (size_t)(n0 + row) * EMB + ks;
    }

    const int kqs = (kq ^ ((l15 >> 1) & 3)) * 8;   // reader bank swizzle

    f32x4 acc[4][8] = {};

    #define STAGE(buf, k0)                                                        \
        do {                                                                      \
            __builtin_amdgcn_global_load_lds(                                     \
                (const __attribute__((address_space(1))) void*)(a0p + (k0)),      \
                (__attribute__((address_space(3))) void*)(sA[buf] + a_c0 * 8), 16, 0, 0); \
            __builtin_amdgcn_global_load_lds(                                     \
                (const __attribute__((address_space(1))) void*)(a1p + (k0)),      \
                (__attribute__((address_space(3))) void*)(sA[buf] + a_c1 * 8), 16, 0, 0); \
            __builtin_amdgcn_global_load_lds(                                     \
                (const __attribute__((address_space(1))) void*)(bp[0] + (k0)),    \
                (__attribute__((address_space(3))) void*)(sB[buf] + b_c[0] * 8), 16, 0, 0); \
            __builtin_amdgcn_global_load_lds(                                     \
                (const __attribute__((address_space(1))) void*)(bp[1] + (k0)),    \
                (__attribute__((address_space(3))) void*)(sB[buf] + b_c[1] * 8), 16, 0, 0); \
            __builtin_amdgcn_global_load_lds(                                     \
                (const __attribute__((address_space(1))) void*)(bp[2] + (k0)),    \
                (__attribute__((address_space(3))) void*)(sB[buf] + b_c[2] * 8), 16, 0, 0); \
            __builtin_amdgcn_global_load_lds(                                     \
                (const __attribute__((address_space(1))) void*)(bp[3] + (k0)),    \
                (__attribute__((address_space(3))) void*)(sB[buf] + b_c[3] * 8), 16, 0, 0); \
        } while (0)

    STAGE(0, 0);

    const int NIT = EMB / 32;   // 24
    for (int it = 0; it < NIT; ++it) {
        const int cur = it & 1;
        if (it + 1 < NIT) {
            STAGE(cur ^ 1, (it + 1) * 32);
            asm volatile("s_waitcnt vmcnt(6)" ::: "memory");  // tile `it` landed
        } else {
            asm volatile("s_waitcnt vmcnt(0)" ::: "memory");
        }
        __builtin_amdgcn_s_barrier();
        asm volatile("" ::: "memory");

        bf16x8 af[4], bfr[8];
        #pragma unroll
        for (int i = 0; i < 4; ++i)
            af[i] = *(const bf16x8*)(sA[cur] + (64 * wr + 16 * i + l15) * 32 + kqs);
        #pragma unroll
        for (int j = 0; j < 8; ++j)
            bfr[j] = *(const bf16x8*)(sB[cur] + (128 * wc + 16 * j + l15) * 32 + kqs);

        #pragma unroll
        for (int i = 0; i < 4; ++i)
            #pragma unroll
            for (int j = 0; j < 8; ++j)
                acc[i][j] = __builtin_amdgcn_mfma_f32_16x16x32_bf16(af[i], bfr[j], acc[i][j], 0, 0, 0);

        asm volatile("s_waitcnt lgkmcnt(0)" ::: "memory");
        __builtin_amdgcn_s_barrier();
        asm volatile("" ::: "memory");
    }
    #undef STAGE

    // C/D: col = lane&15, row = (lane>>4)*4 + reg
    const int kq4 = kq * 4;
    #pragma unroll
    for (int j = 0; j < 8; ++j) {
        int n = n0 + 128 * wc + 16 * j + l15;
        float bv = bflo((uint32_t)bias[n]);
        #pragma unroll
        for (int i = 0; i < 4; ++i) {
            #pragma unroll
            for (int r = 0; r < 4; ++r) {
                int m = m0 + 64 * wr + 16 * i + kq4 + r;
                if (m < M) {
                    float v = acc[i][j][r] + bv;
                    if (outf32) ((float*)p.out[z])[(size_t)m * EMB + n] = v;
                    else        ((uint16_t*)p.out[z])[(size_t)m * EMB + n] = f2bf(v);
                }
            }
        }
    }
}

// ---------------------------------------------------------------- attention (MFMA)
#define RV 264   // sVt row stride (keys)
#define RP 72    // sP row stride
__global__ __launch_bounds__(256) void attn_kernel(const uint16_t* __restrict__ Qg,
                                                   const uint16_t* __restrict__ Kg,
                                                   const uint16_t* __restrict__ Vg,
                                                   uint16_t* __restrict__ Og)
{
    __shared__ __align__(16) uint16_t sVt[HD * RV];
    __shared__ __align__(16) uint16_t sP[4][64 * RP];

    const int bh  = blockIdx.x;
    const size_t base = (size_t)bh * SHD;
    const int tid  = threadIdx.x;
    const int lane = tid & 63;
    const int w    = tid >> 6;
    const int l15  = lane & 15;
    const int kq   = lane >> 4;
    uint16_t* sPw = sP[w];

    {
        int r = tid >> 2, t4 = tid & 3;
        for (int c = SEQ + t4; c < RV; c += 4) sVt[r * RV + c] = 0;
    }
    for (int idx = tid; idx < SHD / 8; idx += 256) {
        int key = idx >> 3, dc = idx & 7;
        uint4 v = ((const uint4*)(Vg + base))[idx];
        uint16_t e[8];
        *(uint4*)e = v;
        #pragma unroll
        for (int j = 0; j < 8; ++j) sVt[(dc * 8 + j) * RV + key] = e[j];
    }

    bf16x8 aq[4][2];
    #pragma unroll
    for (int mi = 0; mi < 4; ++mi) {
        int m = 64 * w + 16 * mi + l15; if (m >= SEQ) m = SEQ - 1;
        const uint16_t* qp = Qg + base + (size_t)m * HD + kq * 8;
        aq[mi][0] = *(const bf16x8*)(qp);
        aq[mi][1] = *(const bf16x8*)(qp + 32);
    }

    bf16x8 ones;
    #pragma unroll
    for (int j = 0; j < 8; ++j) ones[j] = (short)0x3F80;

    f32x4 oacc[4][4] = {};
    f32x4 lacc[4]    = {};

    __syncthreads();   // sVt ready

    for (int c = 0; c < 4; ++c) {
        bf16x8 bk[4][2];
        #pragma unroll
        for (int ni = 0; ni < 4; ++ni) {
            int key = 64 * c + 16 * ni + l15; if (key >= SEQ) key = SEQ - 1;
            const uint16_t* kp = Kg + base + (size_t)key * HD + kq * 8;
            bk[ni][0] = *(const bf16x8*)(kp);
            bk[ni][1] = *(const bf16x8*)(kp + 32);
        }
        #pragma unroll
        for (int mi = 0; mi < 4; ++mi) {
            #pragma unroll
            for (int ni = 0; ni < 4; ++ni) {
                f32x4 s = {};
                s = __builtin_amdgcn_mfma_f32_16x16x32_bf16(aq[mi][0], bk[ni][0], s, 0, 0, 0);
                s = __builtin_amdgcn_mfma_f32_16x16x32_bf16(aq[mi][1], bk[ni][1], s, 0, 0, 0);
                int col = 16 * ni + l15;
                int key = 64 * c + col;
                #pragma unroll
                for (int r = 0; r < 4; ++r) {
                    float pv = (key < SEQ) ? __expf(fminf(s[r], 80.f)) : 0.f;
                    sPw[(16 * mi + kq * 4 + r) * RP + col] = f2bf(pv);
                }
            }
        }

        bf16x8 bv[2][4];
        #pragma unroll
        for (int kk = 0; kk < 2; ++kk)
            #pragma unroll
            for (int ni = 0; ni < 4; ++ni)
                bv[kk][ni] = *(const bf16x8*)(sVt + (16 * ni + l15) * RV + c * 64 + kk * 32 + kq * 8);

        #pragma unroll
        for (int mi = 0; mi < 4; ++mi) {
            #pragma unroll
            for (int kk = 0; kk < 2; ++kk) {
                bf16x8 ap = *(const bf16x8*)(sPw + (16 * mi + l15) * RP + kk * 32 + kq * 8);
                lacc[mi] = __builtin_amdgcn_mfma_f32_16x16x32_bf16(ap, ones, lacc[mi], 0, 0, 0);
                #pragma unroll
                for (int ni = 0; ni < 4; ++ni)
                    oacc[mi][ni] = __builtin_amdgcn_mfma_f32_16x16x32_bf16(ap, bv[kk][ni], oacc[mi][ni], 0, 0, 0);
            }
        }
    }

    #pragma unroll
    for (int mi = 0; mi < 4; ++mi) {
        #pragma unroll
        for (int r = 0; r < 4; ++r) {
            int m = 64 * w + 16 * mi + kq * 4 + r;
            if (m < SEQ) {
                float scale = 1.f / (lacc[mi][r] * 27.712812921102035f);
                #pragma unroll
                for (int ni = 0; ni < 4; ++ni)
                    Og[base + (size_t)m * HD + 16 * ni + l15] = f2bf(oacc[mi][ni][r] * scale);
            }
        }
    }
}

// ---------------------------------------------------------------- launch
extern "C" void kernel_launch(void* const* d_in, const int* in_sizes, int n_in,
                              void* d_out, int out_size, void* d_ws, size_t ws_size,
                              hipStream_t stream)
{
    const size_t NX = (size_t)M_TOK * EMB;
    const size_t NW = (size_t)EMB * EMB;
    const size_t NB = EMB;

    uint16_t* xbf = (uint16_t*)d_ws;
    uint16_t* Wbf[4]; uint16_t* bbf[4];
    uint16_t* cur = xbf + NX;
    for (int i = 0; i < 4; ++i) { Wbf[i] = cur; cur += NW; }
    for (int i = 0; i < 4; ++i) { bbf[i] = cur; cur += NB; }
    uint16_t* Qw = cur;
    uint16_t* Kw = Qw + NX;
    uint16_t* Vw = Kw + NX;

    const size_t need_primary  = 2 * (NX + 4 * NW + 4 * NB + 3 * NX);
    const size_t need_fallback = need_primary - 2 * NX;
    if (ws_size < need_fallback) return;
    if (ws_size < need_primary) Vw = (uint16_t*)d_out;

    CvtJobs jobs;
    jobs.j[0] = { (const float*)d_in[0], xbf,    (int)(NX / 8) };
    jobs.j[1] = { (const float*)d_in[1], Wbf[0], (int)(NW / 8) };
    jobs.j[2] = { (const float*)d_in[3], Wbf[1], (int)(NW / 8) };
    jobs.j[3] = { (const float*)d_in[5], Wbf[2], (int)(NW / 8) };
    jobs.j[4] = { (const float*)d_in[7], Wbf[3], (int)(NW / 8) };
    jobs.j[5] = { (const float*)d_in[2], bbf[0], (int)(NB / 8) };
    jobs.j[6] = { (const float*)d_in[4], bbf[1], (int)(NB / 8) };
    jobs.j[7] = { (const float*)d_in[6], bbf[2], (int)(NB / 8) };
    jobs.j[8] = { (const float*)d_in[8], bbf[3], (int)(NB / 8) };
    const int total8 = (int)((NX + 4 * NW + 4 * NB) / 8);
    convert_kernel<<<(total8 + 255) / 256, 256, 0, stream>>>(jobs);

    const int MT = (M_TOK + 127) / 128;   // 99 m-tiles

    GemmPtrs qkv;
    qkv.W[0] = Wbf[0]; qkv.W[1] = Wbf[1]; qkv.W[2] = Wbf[2];
    qkv.b[0] = bbf[0]; qkv.b[1] = bbf[1]; qkv.b[2] = bbf[2];
    qkv.out[0] = Qw; qkv.out[1] = Kw; qkv.out[2] = Vw;
    const int tot1 = MT * 9;              // 9 n-tiles of 256 across Q,K,V
    gemm_bias_nt<<<tot1, 256, 0, stream>>>(xbf, qkv, M_TOK, tot1, 9, 0);

    attn_kernel<<<dim3(BSZ * NH), 256, 0, stream>>>(Qw, Kw, Vw, Qw);

    GemmPtrs pr;
    pr.W[0] = pr.W[1] = pr.W[2] = Wbf[3];
    pr.b[0] = pr.b[1] = pr.b[2] = bbf[3];
    pr.out[0] = pr.out[1] = pr.out[2] = d_out;
    const int tot2 = MT * 3;              // 3 n-tiles of 256
    gemm_bias_nt<<<tot2, 256, 0, stream>>>(Qw, pr, M_TOK, tot2, 3, 1);
}